// Round 10
// baseline (16.109 us; speedup 1.0000x reference)
//
#include <hip/hip_runtime.h>

#define BATCH   512
#define NPRED   1176
#define HALF    588
#define NTGT    64
#define PRED_C  9
#define THREADS 512
#define NWAVE   8
#define SEGCAP  76                     // >= max per-wave chunk (74)
#define NMASKW  37                     // ceil(1176/32)
#define INVALID_S 0xFFFFu
#define INVALID_U 0xFFFFFFFFu

__device__ __forceinline__ float fexp(float x)  { return __expf(x); }
__device__ __forceinline__ float flog(float x)  { return __logf(x); }

// ---- K1: one block per HALF-batch (grid = 2*BATCH) ----
__global__ __launch_bounds__(THREADS) void det_k1(
    const float* __restrict__ pred,   // (B, N, 9)
    const float* __restrict__ tbox,   // (B, T, 4)
    float2* __restrict__ iu,          // (2B, 64) {inter, uni}
    unsigned int* __restrict__ idxb,  // (2B, 64) batch-rel n or INVALID
    float* __restrict__ bce)          // (2B,) partial conf-BCE sums
{
    __shared__ float4 cbox[NWAVE * SEGCAP];
    __shared__ float  carea[NWAVE * SEGCAP];
    __shared__ unsigned short cidx[NWAVE * SEGCAP];
    __shared__ float4 stgt[NTGT];
    __shared__ float  sbint[THREADS];
    __shared__ float  sbuni[THREADS];
    __shared__ unsigned short sbslot[THREADS];
    __shared__ float  shull[4];
    __shared__ float  sred[NWAVE];

    const int bh  = blockIdx.x, b = bh >> 1, h = bh & 1;
    const int tid = threadIdx.x, wv = tid >> 6, ln = tid & 63;
    const float* pb = pred + (size_t)b * NPRED * PRED_C;

    // ---- targets + hull (wave 0) ----
    if (tid < NTGT) {
        float4 tb = *reinterpret_cast<const float4*>(
            tbox + ((size_t)b * NTGT + tid) * 4);
        stgt[tid] = tb;
        float x1 = tb.x, y1 = tb.y, x2 = tb.z, y2 = tb.w;
        for (int off = 32; off > 0; off >>= 1) {
            x1 = fminf(x1, __shfl_xor(x1, off));
            y1 = fminf(y1, __shfl_xor(y1, off));
            x2 = fmaxf(x2, __shfl_xor(x2, off));
            y2 = fmaxf(y2, __shfl_xor(y2, off));
        }
        if (tid == 0) {
            shull[0] = x1; shull[1] = y1; shull[2] = x2; shull[3] = y2;
        }
    }
    __syncthreads();

    const float hx1 = shull[0], hy1 = shull[1];
    const float hx2 = shull[2], hy2 = shull[3];

    // ---- decode + conf-BCE + cull + wave-local compaction ----
    // wave wv owns batch-rel n in [lo, hi): ascending within wave, ascending
    // across waves, half 0 before half 1 => global ascending order.
    const int lo = h * HALF + (wv * HALF) / NWAVE;
    const int hi = h * HALF + ((wv + 1) * HALF) / NWAVE;
    const int cnt = hi - lo;                       // 73 or 74
    float s_conf = 0.f;
    int wcount = 0;
    for (int i = 0; i < 2; ++i) {                  // ceil(74/64) == 2
        int r = i * 64 + ln;
        int n = lo + r;
        bool keep = false;
        float4 bb; float area = 0.f;
        if (r < cnt) {
            const float* p = pb + n * PRED_C;
            float p0 = p[0], p1 = p[1], p2 = p[2], p3 = p[3], p4 = p[4];
            float cx = (p0 * 2.f - 1.f) * 736.f;   // IMG_W/2
            float cy = (p1 * 2.f - 1.f) * 416.f;   // IMG_H/2
            float w  = fexp(p2) * 32.f;            // 1472/46 == 32 exactly
            float hh = fexp(p3) * 32.f;            // 832/26  == 32 exactly
            bb = make_float4(cx - 0.5f * w, cy - 0.5f * hh,
                             cx + 0.5f * w, cy + 0.5f * hh);
            area = w * hh;
            s_conf += fmaxf(p4, 0.f) + flog(1.f + fexp(-fabsf(p4)));
            keep = (bb.x < hx2) & (bb.z > hx1) & (bb.y < hy2) & (bb.w > hy1);
        }
        unsigned long long m = __ballot(keep);
        if (keep) {
            int pos  = wcount + __popcll(m & ((1ull << ln) - 1ull));
            int slot = wv * SEGCAP + pos;
            cbox[slot]  = bb;
            carea[slot] = area;
            cidx[slot]  = (unsigned short)n;
        }
        wcount += __popcll(m);                     // wave-uniform
    }
    // wave-private segment: own writes complete, no block barrier needed
    asm volatile("s_waitcnt lgkmcnt(0)" ::: "memory");

    // ---- per-target partial argmax over this wave's segment ----
    {
        float4 tb = stgt[ln];
        float a2 = (tb.z - tb.x) * (tb.w - tb.y);
        float binter = 0.f, buni = 1.f;
        int   bslot = INVALID_S;
        const int base = wv * SEGCAP;
        for (int j = 0; j < wcount; ++j) {
            float4 bb = cbox[base + j];            // LDS broadcast
            float a1  = carea[base + j];
            float ix1 = fmaxf(bb.x, tb.x);
            float iy1 = fmaxf(bb.y, tb.y);
            float ix2 = fminf(bb.z, tb.z);
            float iy2 = fminf(bb.w, tb.w);
            float iw  = fmaxf(ix2 - ix1, 0.f);
            float ih  = fmaxf(iy2 - iy1, 0.f);
            float inter = iw * ih;
            float uni   = (a1 + a2) - inter;
            bool better = inter * buni > binter * uni;  // strict: first wins
            binter = better ? inter : binter;
            buni   = better ? uni   : buni;
            bslot  = better ? (base + j) : bslot;
        }
        sbint[tid] = binter; sbuni[tid] = buni;
        sbslot[tid] = (unsigned short)bslot;
    }
    __syncthreads();

    // ---- combine 8 waves (ascending), publish per-target result ----
    if (tid < NTGT) {
        float binter = sbint[tid], buni = sbuni[tid];
        int   bslot = sbslot[tid];
        for (int w = 1; w < NWAVE; ++w) {
            float ci = sbint[w * 64 + tid];
            float cu = sbuni[w * 64 + tid];
            bool better = ci * buni > binter * cu;
            binter = better ? ci : binter;
            buni   = better ? cu : buni;
            bslot  = better ? sbslot[w * 64 + tid] : bslot;
        }
        unsigned int n = (bslot == (int)INVALID_S) ? INVALID_U
                                                   : (unsigned int)cidx[bslot];
        iu[(size_t)bh * NTGT + tid]   = make_float2(binter, buni);
        idxb[(size_t)bh * NTGT + tid] = n;
    }

    // ---- conf-BCE block reduction ----
    float v = s_conf;
    for (int off = 32; off > 0; off >>= 1)
        v += __shfl_down(v, off);
    if (ln == 0) sred[wv] = v;
    __syncthreads();
    if (tid == 0) {
        float t = 0.f;
        for (int i = 0; i < NWAVE; ++i) t += sred[i];
        bce[bh] = t;
    }
}

// ---- K2: one 64-thread block per batch; combine halves + epilogue ----
__global__ __launch_bounds__(64) void det_k2(
    const float* __restrict__ pred,
    const float* __restrict__ tbox,
    const int*   __restrict__ tcls,
    const float2* __restrict__ iu,
    const unsigned int* __restrict__ idxb,
    const float* __restrict__ bce,
    float* __restrict__ partial)
{
    __shared__ unsigned int smask[NMASKW];
    const int b = blockIdx.x, t = threadIdx.x;
    if (t < NMASKW) smask[t] = 0u;

    float2 a0 = iu[((size_t)b * 2 + 0) * NTGT + t];
    float2 a1 = iu[((size_t)b * 2 + 1) * NTGT + t];
    unsigned int n0 = idxb[((size_t)b * 2 + 0) * NTGT + t];
    unsigned int n1 = idxb[((size_t)b * 2 + 1) * NTGT + t];
    bool better = a1.x * a0.y > a0.x * a1.y;       // strict: half 0 wins ties
    unsigned int n = better ? n1 : n0;
    const int m = (n == INVALID_U) ? 0 : (int)n;   // all-zero IoU -> argmax 0

    __syncthreads();
    atomicOr(&smask[m >> 5], 1u << (m & 31));      // set semantics

    const float* pm = pred + (size_t)b * NPRED * PRED_C + m * PRED_C;
    float p0 = pm[0], p1 = pm[1], p2 = pm[2], p3 = pm[3];
    float cx = (p0 * 2.f - 1.f) * 736.f;
    float cy = (p1 * 2.f - 1.f) * 416.f;
    float w  = fexp(p2) * 32.f;
    float hh = fexp(p3) * 32.f;
    float bx1 = cx - 0.5f * w, by1 = cy - 0.5f * hh;
    float bx2 = cx + 0.5f * w, by2 = cy + 0.5f * hh;

    float4 tb = *reinterpret_cast<const float4*>(
        tbox + ((size_t)b * NTGT + t) * 4);
    float s_box = 0.f, d;
    d = fabsf(bx1 - tb.x); s_box += (d < 1.f) ? 0.5f * d * d : d - 0.5f;
    d = fabsf(by1 - tb.y); s_box += (d < 1.f) ? 0.5f * d * d : d - 0.5f;
    d = fabsf(bx2 - tb.z); s_box += (d < 1.f) ? 0.5f * d * d : d - 0.5f;
    d = fabsf(by2 - tb.w); s_box += (d < 1.f) ? 0.5f * d * d : d - 0.5f;

    float x0 = pm[5], x1 = pm[6], x2 = pm[7], x3 = pm[8];
    float mx = fmaxf(fmaxf(x0, x1), fmaxf(x2, x3));
    float se = fexp(x0 - mx) + fexp(x1 - mx) + fexp(x2 - mx) + fexp(x3 - mx);
    float lse = mx + flog(se);
    int tc = tcls[(size_t)b * NTGT + t];
    float xt = (tc == 0) ? x0 : (tc == 1) ? x1 : (tc == 2) ? x2 : x3;
    float s_cls = lse - xt;

    __syncthreads();                               // all atomicOrs visible

    // deterministic dedup sum: fixed word/bit order per lane
    float s_pos = 0.f;
    if (t < NMASKW) {
        unsigned int mw = smask[t];
        while (mw) {
            int bit = __ffs(mw) - 1; mw &= mw - 1;
            int mm = t * 32 + bit;
            s_pos += pred[(size_t)b * NPRED * PRED_C + mm * PRED_C + 4];
        }
    }

    float v = 5.f * s_box + s_cls - s_pos;
    if (t == 0) v += bce[(size_t)b * 2] + bce[(size_t)b * 2 + 1];
    for (int off = 32; off > 0; off >>= 1)
        v += __shfl_down(v, off);
    if (t == 0) partial[b] = v;
}

__global__ __launch_bounds__(BATCH) void det_k3(
    const float* __restrict__ partial, float* __restrict__ out)
{
    int tid = threadIdx.x;
    float v = partial[tid];
    for (int off = 32; off > 0; off >>= 1)
        v += __shfl_down(v, off);
    __shared__ float s[8];
    if ((tid & 63) == 0) s[tid >> 6] = v;
    __syncthreads();
    if (tid == 0) {
        float t = 0.f;
        for (int i = 0; i < 8; ++i) t += s[i];
        *out = t * (1.f / BATCH);
    }
}

extern "C" void kernel_launch(void* const* d_in, const int* in_sizes, int n_in,
                              void* d_out, int out_size, void* d_ws, size_t ws_size,
                              hipStream_t stream) {
    const float* pred = (const float*)d_in[0];
    const float* tbox = (const float*)d_in[1];
    const int*   tcls = (const int*)d_in[2];
    float* out = (float*)d_out;

    // ws layout (all fully overwritten each call before being read)
    float2*       iu      = (float2*)d_ws;                         // 512 KB
    unsigned int* idxb    = (unsigned int*)((char*)d_ws + 524288); // 256 KB
    float*        bce     = (float*)((char*)d_ws + 786432);        //   4 KB
    float*        partial = (float*)((char*)d_ws + 790528);        //   2 KB

    det_k1<<<2 * BATCH, THREADS, 0, stream>>>(pred, tbox, iu, idxb, bce);
    det_k2<<<BATCH, 64, 0, stream>>>(pred, tbox, tcls, iu, idxb, bce, partial);
    det_k3<<<1, BATCH, 0, stream>>>(partial, out);
}

// Round 11
// 13.668 us; speedup vs baseline: 1.1785x; 1.1785x over previous
//
#include <hip/hip_runtime.h>

#define BATCH   512
#define NPRED   1176
#define NTGT    64
#define PRED_C  9
#define THREADS 1024
#define NWAVE   16
#define SEGCAP  76                     // >= max per-wave chunk (74)
#define NMASKW  ((NPRED + 31) / 32)    // 37
#define INVALID 0xFFFF

// fast transcendentals: map to v_exp_f32 / v_log_f32 sequences
__device__ __forceinline__ float fexp(float x)  { return __expf(x); }
__device__ __forceinline__ float flog(float x)  { return __logf(x); }

__global__ __launch_bounds__(THREADS) void det_loss_main(
    const float* __restrict__ pred,   // (B, N, 9)
    const float* __restrict__ tbox,   // (B, T, 4)
    const int*   __restrict__ tcls,   // (B, T)
    float* __restrict__ partial)      // (B,)
{
    __shared__ float4 cbox[NWAVE * SEGCAP];        // kept boxes, per-wave segments
    __shared__ float  carea[NWAVE * SEGCAP];
    __shared__ unsigned short cidx[NWAVE * SEGCAP];
    __shared__ float4 stgt[NTGT];
    __shared__ float  slogit[NPRED];
    __shared__ unsigned int smask[NMASKW];
    __shared__ float  sbint[THREADS];
    __shared__ float  sbuni[THREADS];
    __shared__ unsigned short sbslot[THREADS];
    __shared__ float  shull[4];
    __shared__ float  sred[NWAVE];

    const int b   = blockIdx.x;
    const int tid = threadIdx.x;
    const int wv  = tid >> 6, ln = tid & 63;
    const float* pb = pred + (size_t)b * NPRED * PRED_C;

    if (tid < NMASKW) smask[tid] = 0u;

    // ---- targets + hull (wave 0 only) ----
    if (tid < NTGT) {
        float4 tb = *reinterpret_cast<const float4*>(
            tbox + ((size_t)b * NTGT + tid) * 4);
        stgt[tid] = tb;
        float x1 = tb.x, y1 = tb.y, x2 = tb.z, y2 = tb.w;
        for (int off = 32; off > 0; off >>= 1) {
            x1 = fminf(x1, __shfl_xor(x1, off));
            y1 = fminf(y1, __shfl_xor(y1, off));
            x2 = fmaxf(x2, __shfl_xor(x2, off));
            y2 = fmaxf(y2, __shfl_xor(y2, off));
        }
        if (tid == 0) {
            shull[0] = x1; shull[1] = y1; shull[2] = x2; shull[3] = y2;
        }
    }
    __syncthreads();

    const float hx1 = shull[0], hy1 = shull[1];
    const float hx2 = shull[2], hy2 = shull[3];

    // ---- fused decode + conf-BCE + hull-cull + wave-local compaction ----
    // wave wv owns contiguous n in [lo, hi): ascending-n within wave and
    // ascending-wave across waves => first-max tie-break preserved.
    const int lo  = (wv * NPRED) / NWAVE;
    const int hi  = ((wv + 1) * NPRED) / NWAVE;
    const int cnt = hi - lo;                       // 73 or 74
    float s_conf = 0.f;
    int wcount = 0;
    for (int i = 0; i < 2; ++i) {                  // ceil(74/64) == 2
        int r = i * 64 + ln;
        int n = lo + r;
        bool keep = false;
        float4 bb; float area = 0.f;
        if (r < cnt) {
            const float* p = pb + n * PRED_C;
            float p0 = p[0], p1 = p[1], p2 = p[2], p3 = p[3], p4 = p[4];
            float cx = (p0 * 2.f - 1.f) * 736.f;   // IMG_W/2
            float cy = (p1 * 2.f - 1.f) * 416.f;   // IMG_H/2
            float w  = fexp(p2) * 32.f;            // 1472/46 == 32 exactly
            float h  = fexp(p3) * 32.f;            // 832/26  == 32 exactly
            bb = make_float4(cx - 0.5f * w, cy - 0.5f * h,
                             cx + 0.5f * w, cy + 0.5f * h);
            area = w * h;
            slogit[n] = p4;
            // logaddexp(0,x) = max(x,0) + log(1 + exp(-|x|))
            s_conf += fmaxf(p4, 0.f) + flog(1.f + fexp(-fabsf(p4)));
            keep = (bb.x < hx2) & (bb.z > hx1) & (bb.y < hy2) & (bb.w > hy1);
        }
        unsigned long long m = __ballot(keep);
        if (keep) {
            int pos  = wcount + __popcll(m & ((1ull << ln) - 1ull));
            int slot = wv * SEGCAP + pos;
            cbox[slot]  = bb;
            carea[slot] = area;
            cidx[slot]  = (unsigned short)n;
        }
        wcount += __popcll(m);                     // wave-uniform
    }
    __syncthreads();

    // ---- Phase B: per-target partial argmax over this wave's segment ----
    {
        float4 tb = stgt[ln];
        float a2 = (tb.z - tb.x) * (tb.w - tb.y);
        float binter = 0.f, buni = 1.f;
        int   bslot = INVALID;
        const int base = wv * SEGCAP;
        for (int j = 0; j < wcount; ++j) {
            float4 bb = cbox[base + j];            // LDS broadcast
            float a1  = carea[base + j];
            float ix1 = fmaxf(bb.x, tb.x);
            float iy1 = fmaxf(bb.y, tb.y);
            float ix2 = fminf(bb.z, tb.z);
            float iy2 = fminf(bb.w, tb.w);
            float iw  = fmaxf(ix2 - ix1, 0.f);
            float ih  = fmaxf(iy2 - iy1, 0.f);
            float inter = iw * ih;
            float uni   = (a1 + a2) - inter;
            bool better = inter * buni > binter * uni;  // strict: first wins
            binter = better ? inter : binter;
            buni   = better ? uni   : buni;
            bslot  = better ? (base + j) : bslot;
        }
        sbint[tid] = binter; sbuni[tid] = buni;
        sbslot[tid] = (unsigned short)bslot;
    }
    __syncthreads();

    // ---- Phase C (lanes 0..63): combine waves, box + cls loss, mask ----
    float s_box = 0.f, s_cls = 0.f;
    if (tid < NTGT) {
        float binter = sbint[tid], buni = sbuni[tid];
        int   bslot = sbslot[tid];
        for (int w = 1; w < NWAVE; ++w) {          // ascending: first-max wins
            float ci = sbint[w * 64 + tid];
            float cu = sbuni[w * 64 + tid];
            bool better = ci * buni > binter * cu;
            binter = better ? ci : binter;
            buni   = better ? cu : buni;
            bslot  = better ? sbslot[w * 64 + tid] : bslot;
        }
        int m; float4 pbx;
        if (bslot == INVALID) {                    // all IoU == 0 -> argmax = 0
            m = 0;
            float p0 = pb[0], p1 = pb[1], p2 = pb[2], p3 = pb[3];
            float cx = (p0 * 2.f - 1.f) * 736.f;
            float cy = (p1 * 2.f - 1.f) * 416.f;
            float w  = fexp(p2) * 32.f;
            float h  = fexp(p3) * 32.f;
            pbx = make_float4(cx - 0.5f * w, cy - 0.5f * h,
                              cx + 0.5f * w, cy + 0.5f * h);
        } else {
            m = cidx[bslot];
            pbx = cbox[bslot];
        }
        atomicOr(&smask[m >> 5], 1u << (m & 31));  // set semantics, deterministic

        float4 tb = stgt[tid];
        float d;
        d = fabsf(pbx.x - tb.x); s_box += (d < 1.f) ? 0.5f * d * d : d - 0.5f;
        d = fabsf(pbx.y - tb.y); s_box += (d < 1.f) ? 0.5f * d * d : d - 0.5f;
        d = fabsf(pbx.z - tb.z); s_box += (d < 1.f) ? 0.5f * d * d : d - 0.5f;
        d = fabsf(pbx.w - tb.w); s_box += (d < 1.f) ? 0.5f * d * d : d - 0.5f;

        const float* pc = pb + m * PRED_C + 5;
        float x0 = pc[0], x1 = pc[1], x2 = pc[2], x3 = pc[3];
        float mx = fmaxf(fmaxf(x0, x1), fmaxf(x2, x3));
        float se = fexp(x0 - mx) + fexp(x1 - mx) + fexp(x2 - mx) + fexp(x3 - mx);
        float lse = mx + flog(se);
        int tc = tcls[(size_t)b * NTGT + tid];
        float xt = (tc == 0) ? x0 : (tc == 1) ? x1 : (tc == 2) ? x2 : x3;
        s_cls += lse - xt;
    }
    __syncthreads();

    // ---- Phase D: subtract matched conf logits (deduped via bitmask) ----
    float s_pos = 0.f;
    for (int n = tid; n < NPRED; n += THREADS)
        if (smask[n >> 5] & (1u << (n & 31))) s_pos += slogit[n];

    // ---- block reduction of conf - pos + 5*box + cls ----
    float v = s_conf - s_pos + 5.f * s_box + s_cls;
    for (int off = 32; off > 0; off >>= 1)
        v += __shfl_down(v, off);
    if (ln == 0) sred[wv] = v;
    __syncthreads();
    if (tid == 0) {
        float t = 0.f;
        for (int i = 0; i < NWAVE; ++i) t += sred[i];
        partial[b] = t;
    }
}

__global__ __launch_bounds__(BATCH) void det_loss_final(
    const float* __restrict__ partial, float* __restrict__ out)
{
    int tid = threadIdx.x;
    float v = partial[tid];
    for (int off = 32; off > 0; off >>= 1)
        v += __shfl_down(v, off);
    __shared__ float s[8];
    if ((tid & 63) == 0) s[tid >> 6] = v;
    __syncthreads();
    if (tid == 0) {
        float t = 0.f;
        for (int i = 0; i < 8; ++i) t += s[i];
        *out = t * (1.f / BATCH);
    }
}

extern "C" void kernel_launch(void* const* d_in, const int* in_sizes, int n_in,
                              void* d_out, int out_size, void* d_ws, size_t ws_size,
                              hipStream_t stream) {
    const float* pred = (const float*)d_in[0];
    const float* tbox = (const float*)d_in[1];
    const int*   tcls = (const int*)d_in[2];
    float* out     = (float*)d_out;
    float* partial = (float*)d_ws;   // 512 floats, overwritten every call

    det_loss_main<<<BATCH, THREADS, 0, stream>>>(pred, tbox, tcls, partial);
    det_loss_final<<<1, BATCH, 0, stream>>>(partial, out);
}